// Round 2
// baseline (117.375 us; speedup 1.0000x reference)
//
#include <hip/hip_runtime.h>
#include <math.h>

typedef __attribute__((ext_vector_type(8))) short bf16x8;
typedef __attribute__((ext_vector_type(4))) float f32x4;

#define MFMA(a, b, c) __builtin_amdgcn_mfma_f32_16x16x32_bf16(a, b, c, 0, 0, 0)

constexpr int GN = 128;   // B*T
constexpr int NN = 512;   // nodes
constexpr int FD = 128;   // F_in == D == 128
#define LOG2E 1.4426950408889634f

// round-to-nearest-even bf16 kept in the TOP 16 bits of a u32
__device__ inline unsigned rne_top16(float x) {
    unsigned u = __float_as_uint(x);
    return u + 0x7fffu + ((u >> 16) & 1u);
}
// pack top-16 of e0 (-> low half) and e1 (-> high half)
__device__ inline unsigned pack_top16(unsigned e1, unsigned e0) {
    return __builtin_amdgcn_perm(e1, e0, 0x07060302u);
}

// ---------------------------------------------------------------------------
// ONE fused kernel. 256 blocks = (g, half), 512 threads (8 waves), 148 KB LDS.
// Both half-blocks of a g sit on the same XCD (bid&7 = xcd, g = xcd*16+...)
// so the duplicated h[g] read is an L2 hit for the second block.
//
// Phase 1: full Wh[g] = h@W via 3-split bf16 MFMA (each wave owns 64 j-rows,
//   acc[4][8]). W is staged per-32-k chunk as hi/lo bf16 (16 KB LDS, rebuilt
//   4x per block — trivial). Wh lands in LDS (128 KB) in the MFMA-B-fragment
//   swizzle: elem (j,d) -> ((KK*8+nb)*64+lanep)*8+idx, KK=j>>5, nb=d>>4,
//   lanep=(d&15)+16*((j>>3)&3), idx=j&7 — single RNE bf16 (error analysis
//   from prior session: ~7e-5 after p/l-weighted averaging). esrc/edst
//   (pre-scaled by LOG2E) go to 4 KB LDS.
// Phase 2: attention for the block's 256 i-rows, BARRIER-FREE j-loop:
//   B-fragments read straight from LDS Wh; masking reads adj int4s from L2
//   (1 MB, resident, pipelined one KK ahead); p kept as truncated-top16
//   bf16; lsum via ones-column MFMA (truncation common-mode preserved).
//   No max-subtraction (shift-invariant; masked -> p = 0 exactly).
// ---------------------------------------------------------------------------
__global__ __launch_bounds__(512, 2) void gat_fused_kernel(
    const float* __restrict__ h, const float* __restrict__ a,
    const int* __restrict__ adj, const float* __restrict__ W,
    float* __restrict__ out)
{
    __shared__ __attribute__((aligned(16))) unsigned short sWh[65536]; // 128 KB
    __shared__ __attribute__((aligned(16))) unsigned short sWc[8192];  // 16 KB
    __shared__ __attribute__((aligned(16))) float sEsrc[NN];           // 2 KB
    __shared__ __attribute__((aligned(16))) float sEdst[NN];           // 2 KB

    const int bid = blockIdx.x;
    const int xcd = bid & 7, slot = bid >> 3;
    const int g  = xcd * 16 + (slot >> 1);   // both halves of g on one XCD
    const int hf = slot & 1;
    const int t = threadIdx.x, lane = t & 63, w = t >> 6;
    const int l15 = lane & 15, q8 = (lane >> 4) * 8;
    const float* hg = h + (size_t)g * NN * FD;

    // ================= phase 1: Wh[g] (all 512 rows) =================
    f32x4 acc1[4][8];
    #pragma unroll
    for (int mt = 0; mt < 4; ++mt)
        #pragma unroll
        for (int nb = 0; nb < 8; ++nb) acc1[mt][nb] = (f32x4){0.f, 0.f, 0.f, 0.f};

    // this thread stages B-frag position (nb=w, lanep=lane) of each k-chunk:
    const int sd = w * 16 + l15;             // d column it converts

    #pragma unroll
    for (int kk = 0; kk < 4; ++kk) {
        // h loads (registers only, no LDS) — issue before the barrier
        float4 hv[8];
        #pragma unroll
        for (int mt = 0; mt < 4; ++mt) {
            const float* src = hg + (size_t)(w * 64 + mt * 16 + l15) * FD
                             + kk * 32 + q8;
            hv[2 * mt]     = *(const float4*)src;
            hv[2 * mt + 1] = *(const float4*)(src + 4);
        }

        if (kk > 0) __syncthreads();         // prior chunk's frag reads done
        {   // stage W k-chunk kk: hi/lo split, swizzled
            const int kbase = kk * 32 + q8;
            unsigned hi[8], lo[8];
            #pragma unroll
            for (int idx = 0; idx < 8; ++idx) {
                const float wv = W[(kbase + idx) * FD + sd];
                const unsigned u = __float_as_uint(wv);
                hi[idx] = u;                 // top16 = truncation
                lo[idx] = rne_top16(wv - __uint_as_float(u & 0xffff0000u));
            }
            uint4 H4, L4;
            H4.x = pack_top16(hi[1], hi[0]); H4.y = pack_top16(hi[3], hi[2]);
            H4.z = pack_top16(hi[5], hi[4]); H4.w = pack_top16(hi[7], hi[6]);
            L4.x = pack_top16(lo[1], lo[0]); L4.y = pack_top16(lo[3], lo[2]);
            L4.z = pack_top16(lo[5], lo[4]); L4.w = pack_top16(lo[7], lo[6]);
            *(uint4*)&sWc[t * 8]        = H4;
            *(uint4*)&sWc[4096 + t * 8] = L4;
        }
        __syncthreads();                     // chunk visible

        bf16x8 ah[4], al[4];
        #pragma unroll
        for (int mt = 0; mt < 4; ++mt) {
            const float4 f0 = hv[2 * mt], f1 = hv[2 * mt + 1];
            const float xs[8] = {f0.x, f0.y, f0.z, f0.w, f1.x, f1.y, f1.z, f1.w};
            union { bf16x8 v; unsigned u[4]; } H, L;
            #pragma unroll
            for (int j = 0; j < 4; ++j) {
                const unsigned e0 = __float_as_uint(xs[2 * j]);
                const unsigned e1 = __float_as_uint(xs[2 * j + 1]);
                H.u[j] = pack_top16(e1, e0);
                const unsigned l0 = rne_top16(xs[2*j]   - __uint_as_float(e0 & 0xffff0000u));
                const unsigned l1 = rne_top16(xs[2*j+1] - __uint_as_float(e1 & 0xffff0000u));
                L.u[j] = pack_top16(l1, l0);
            }
            ah[mt] = H.v; al[mt] = L.v;
        }
        #pragma unroll
        for (int nb = 0; nb < 8; ++nb) {
            const bf16x8 bh = *(const bf16x8*)&sWc[(nb * 64 + lane) * 8];
            const bf16x8 bl = *(const bf16x8*)&sWc[4096 + (nb * 64 + lane) * 8];
            #pragma unroll
            for (int mt = 0; mt < 4; ++mt) {
                acc1[mt][nb] = MFMA(al[mt], bh, acc1[mt][nb]);
                acc1[mt][nb] = MFMA(ah[mt], bl, acc1[mt][nb]);
                acc1[mt][nb] = MFMA(ah[mt], bh, acc1[mt][nb]);
            }
        }
    }

    // ---- esrc / edst for this wave's 64 rows -> LDS (pre-scaled LOG2E) ----
    {
        float av[8], bv[8];
        #pragma unroll
        for (int nb = 0; nb < 8; ++nb) {
            av[nb] = a[nb * 16 + l15];
            bv[nb] = a[FD + nb * 16 + l15];
        }
        #pragma unroll
        for (int mt = 0; mt < 4; ++mt)
            #pragma unroll
            for (int r = 0; r < 4; ++r) {
                float ps = 0.f, pd = 0.f;
                #pragma unroll
                for (int nb = 0; nb < 8; ++nb) {
                    ps += acc1[mt][nb][r] * av[nb];
                    pd += acc1[mt][nb][r] * bv[nb];
                }
                #pragma unroll
                for (int off = 1; off <= 8; off <<= 1) {
                    ps += __shfl_xor(ps, off);
                    pd += __shfl_xor(pd, off);
                }
                if (l15 == 0) {
                    const int row = w * 64 + mt * 16 + (lane >> 4) * 4 + r;
                    sEsrc[row] = ps * LOG2E;
                    sEdst[row] = pd * LOG2E;
                }
            }
    }

    // ---- transpose this wave's 64 Wh rows into swizzled LDS (RNE bf16) ----
    {
        const int ib = 4 * ((lane >> 4) & 1);
        #pragma unroll
        for (int mt = 0; mt < 4; ++mt) {
            const int KK = w * 2 + (mt >> 1);
            const int lp2 = l15 + 16 * ((mt & 1) * 2 + (lane >> 5));
            #pragma unroll
            for (int nb = 0; nb < 8; ++nb) {
                const int off = ((KK * 8 + nb) * 64 + lp2) * 8 + ib;
                const unsigned r0 = rne_top16(acc1[mt][nb][0]);
                const unsigned r1 = rne_top16(acc1[mt][nb][1]);
                const unsigned r2 = rne_top16(acc1[mt][nb][2]);
                const unsigned r3 = rne_top16(acc1[mt][nb][3]);
                *(uint2*)&sWh[off] = make_uint2(pack_top16(r1, r0), pack_top16(r3, r2));
            }
        }
    }
    __syncthreads();   // sWh / sEsrc / sEdst complete

    // ================= phase 2: attention, barrier-free =================
    const int rloc0 = w * 32 + l15;                  // within the 256-half
    const int irow0 = hf * 256 + rloc0;              // node index
    const int irow1 = irow0 + 16;
    const float s0 = sEsrc[irow0];
    const float s1 = sEsrc[irow1];
    const int* adjr0 = adj + (size_t)irow0 * NN;
    const int* adjr1 = adj + (size_t)irow1 * NN;

    // register-constant B fragment: ones in column 0 (lane&15==0), else 0
    union { bf16x8 v; unsigned short s[8]; } bo;
    {
        const unsigned short oneb = (l15 == 0) ? (unsigned short)0x3f80 : (unsigned short)0;
        #pragma unroll
        for (int j = 0; j < 8; ++j) bo.s[j] = oneb;
    }

    f32x4 acc[2][8];
    #pragma unroll
    for (int mt = 0; mt < 2; ++mt)
        #pragma unroll
        for (int nb = 0; nb < 8; ++nb) acc[mt][nb] = (f32x4){0.f, 0.f, 0.f, 0.f};
    f32x4 accS0 = (f32x4){0.f, 0.f, 0.f, 0.f};
    f32x4 accS1 = (f32x4){0.f, 0.f, 0.f, 0.f};

    // adj pipelined one KK ahead (L2-resident, 1 MB, shared by all blocks)
    int4 n00 = *(const int4*)&adjr0[q8];
    int4 n01 = *(const int4*)&adjr0[q8 + 4];
    int4 n10 = *(const int4*)&adjr1[q8];
    int4 n11 = *(const int4*)&adjr1[q8 + 4];

    for (int KK = 0; KK < 16; ++KK) {
        const int4 m00 = n00, m01 = n01, m10 = n10, m11 = n11;
        if (KK < 15) {
            const int jb = (KK + 1) * 32 + q8;
            n00 = *(const int4*)&adjr0[jb];
            n01 = *(const int4*)&adjr0[jb + 4];
            n10 = *(const int4*)&adjr1[jb];
            n11 = *(const int4*)&adjr1[jb + 4];
        }
        const float* ep = &sEdst[KK * 32 + q8];
        const float4 ed0 = *(const float4*)ep;
        const float4 ed1 = *(const float4*)(ep + 4);
        const float ev[8] = {ed0.x, ed0.y, ed0.z, ed0.w, ed1.x, ed1.y, ed1.z, ed1.w};
        int ma0[8], ma1[8];
        *(int4*)&ma0[0] = m00; *(int4*)&ma0[4] = m01;
        *(int4*)&ma1[0] = m10; *(int4*)&ma1[4] = m11;

        union { bf16x8 v; unsigned u[4]; } H0, H1;
        unsigned uh0[8], uh1[8];
        #pragma unroll
        for (int i = 0; i < 8; ++i) {
            const float z0 = s0 + ev[i];
            float p0 = __builtin_amdgcn_exp2f(fmaxf(z0, 0.2f * z0));
            p0 = (ma0[i] > 0) ? p0 : 0.f;
            uh0[i] = __float_as_uint(p0);
            const float z1 = s1 + ev[i];
            float p1 = __builtin_amdgcn_exp2f(fmaxf(z1, 0.2f * z1));
            p1 = (ma1[i] > 0) ? p1 : 0.f;
            uh1[i] = __float_as_uint(p1);
        }
        #pragma unroll
        for (int j = 0; j < 4; ++j) {
            H0.u[j] = pack_top16(uh0[2*j+1], uh0[2*j]);   // perm keeps top16 = trunc
            H1.u[j] = pack_top16(uh1[2*j+1], uh1[2*j]);
        }
        #pragma unroll
        for (int nb = 0; nb < 8; ++nb) {
            const bf16x8 bh = *(const bf16x8*)&sWh[((KK * 8 + nb) * 64 + lane) * 8];
            acc[0][nb] = MFMA(H0.v, bh, acc[0][nb]);
            acc[1][nb] = MFMA(H1.v, bh, acc[1][nb]);
        }
        accS0 = MFMA(H0.v, bo.v, accS0);       // row-sums (lsum) in column 0
        accS1 = MFMA(H1.v, bo.v, accS1);
    }

    #pragma unroll
    for (int r = 0; r < 4; ++r) {
        // lsum for output row rr=(lane>>4)*4+r sits at lane (lane&48), reg r, col 0
        const float rl0 = 1.0f / __shfl(accS0[r], lane & 48);
        const float rl1 = 1.0f / __shfl(accS1[r], lane & 48);
        const int row0 = g * NN + hf * 256 + w * 32 + (lane >> 4) * 4 + r;
        const int row1 = row0 + 16;
        #pragma unroll
        for (int nb = 0; nb < 8; ++nb) {
            out[row0 * FD + nb * 16 + l15] = acc[0][nb][r] * rl0;
            out[row1 * FD + nb * 16 + l15] = acc[1][nb][r] * rl1;
        }
    }
}

// ---------------------------------------------------------------------------
extern "C" void kernel_launch(void* const* d_in, const int* in_sizes, int n_in,
                              void* d_out, int out_size, void* d_ws, size_t ws_size,
                              hipStream_t stream) {
    const float* h   = (const float*)d_in[0];
    const int*   adj = (const int*)d_in[1];
    const float* W   = (const float*)d_in[2];
    const float* a   = (const float*)d_in[3];
    float* out = (float*)d_out;
    (void)d_ws; (void)ws_size;   // workspace no longer used — all fused in LDS

    gat_fused_kernel<<<256, 512, 0, stream>>>(h, a, adj, W, out);
}

// Round 3
// 116.944 us; speedup vs baseline: 1.0037x; 1.0037x over previous
//
#include <hip/hip_runtime.h>
#include <math.h>

typedef __attribute__((ext_vector_type(8))) short bf16x8;
typedef __attribute__((ext_vector_type(4))) float f32x4;

#define MFMA(a, b, c) __builtin_amdgcn_mfma_f32_16x16x32_bf16(a, b, c, 0, 0, 0)

constexpr int GN = 128;   // B*T
constexpr int NN = 512;   // nodes
constexpr int FD = 128;   // F_in == D == 128
#define LOG2E 1.4426950408889634f

// round-to-nearest-even bf16 kept in the TOP 16 bits of a u32
__device__ inline unsigned rne_top16(float x) {
    unsigned u = __float_as_uint(x);
    return u + 0x7fffu + ((u >> 16) & 1u);
}
// pack top-16 of e0 (-> low half) and e1 (-> high half)
__device__ inline unsigned pack_top16(unsigned e1, unsigned e0) {
    return __builtin_amdgcn_perm(e1, e0, 0x07060302u);
}

// ---------------------------------------------------------------------------
// ONE fused kernel. 256 blocks = (g, half), 1024 threads (16 waves =
// 4 waves/SIMD — R2 at 8 waves/2-per-SIMD was latency-bound: MfmaUtil 17%,
// VALU 32%, occ 18%). LDS 132 KB -> 1 block/CU; latency hiding comes from
// wave count, not block count. VGPR must stay <=128 unified for 16 waves.
//
// Phase 1: full Wh[g] = h@W via 3-split bf16 MFMA, 16 waves x 32 rows
//   (acc1[2][8] = 64 regs). W hi/lo staged ONCE into the UPPER half of sWh
//   (region is dead until the transpose overwrites it) -> K-loop is
//   barrier-free, no separate sWc. Wh -> lower+upper sWh in B-frag swizzle
//   (elem (j,d) -> ((KK*8+nb)*64+lanep)*8+idx, KK=j>>5, nb=d>>4,
//   lanep=(d&15)+16*((j>>3)&3), idx=j&7), single RNE bf16. esrc/edst
//   (pre-scaled LOG2E) -> 4 KB LDS.
// Phase 2: wave pairs: rg=w>>1 owns 32 i-rows (2 row-tiles, R2's proven
//   loop body), jh=w&1 takes 8 of the 16 KK j-chunks. Keeps B-frag LDS
//   traffic at 1024 reads/block (same as R2) and exp work at 1x per (i,j).
//   Epilogue: jh=1 dumps partial acc into sWh-as-float (dead after loop)
//   and partial row-sums into sEsrc (dead after s0/s1 reg reads); jh=0
//   combines, rescales by 1/lsum, writes out. lsum via ones-column MFMA.
// ---------------------------------------------------------------------------
__global__ __launch_bounds__(1024) void gat_fused_kernel(
    const float* __restrict__ h, const float* __restrict__ a,
    const int* __restrict__ adj, const float* __restrict__ W,
    float* __restrict__ out)
{
    __shared__ __attribute__((aligned(16))) unsigned short sWh[65536]; // 128 KB
    __shared__ __attribute__((aligned(16))) float sEsrc[NN];           // 2 KB
    __shared__ __attribute__((aligned(16))) float sEdst[NN];           // 2 KB

    const int bid = blockIdx.x;
    const int xcd = bid & 7, slot = bid >> 3;
    const int g  = xcd * 16 + (slot >> 1);   // both halves of g on one XCD
    const int hf = slot & 1;
    const int t = threadIdx.x, lane = t & 63, w = t >> 6;   // w in [0,16)
    const int l15 = lane & 15, q8 = (lane >> 4) * 8;
    const float* hg = h + (size_t)g * NN * FD;

    // ---- stage FULL W hi/lo into sWh upper half (dead until transpose) ----
    // hi at short-offset 32768 + p*8, lo at 49152 + p*8, p in [0,2048)
    #pragma unroll
    for (int rep = 0; rep < 2; ++rep) {
        const int p = rep * 1024 + t;
        const int lanep = p & 63, cn2 = p >> 6;        // cn2 = kk*8+nb
        const int kbase = (cn2 >> 3) * 32 + ((lanep >> 4) & 3) * 8;
        const int d = (cn2 & 7) * 16 + (lanep & 15);
        unsigned hi[8], lo[8];
        #pragma unroll
        for (int idx = 0; idx < 8; ++idx) {
            const float wv = W[(kbase + idx) * FD + d];
            const unsigned u = __float_as_uint(wv);
            hi[idx] = u;                               // top16 = truncation
            lo[idx] = rne_top16(wv - __uint_as_float(u & 0xffff0000u));
        }
        uint4 H4, L4;
        H4.x = pack_top16(hi[1], hi[0]); H4.y = pack_top16(hi[3], hi[2]);
        H4.z = pack_top16(hi[5], hi[4]); H4.w = pack_top16(hi[7], hi[6]);
        L4.x = pack_top16(lo[1], lo[0]); L4.y = pack_top16(lo[3], lo[2]);
        L4.z = pack_top16(lo[5], lo[4]); L4.w = pack_top16(lo[7], lo[6]);
        *(uint4*)&sWh[32768 + p * 8] = H4;
        *(uint4*)&sWh[49152 + p * 8] = L4;
    }
    __syncthreads();

    // ================= phase 1: Wh[g], barrier-free K loop =================
    f32x4 acc1[2][8];
    #pragma unroll
    for (int mt = 0; mt < 2; ++mt)
        #pragma unroll
        for (int nb = 0; nb < 8; ++nb) acc1[mt][nb] = (f32x4){0.f, 0.f, 0.f, 0.f};

    #pragma unroll
    for (int kk = 0; kk < 4; ++kk) {
        float4 hv[4];
        #pragma unroll
        for (int mt = 0; mt < 2; ++mt) {
            const float* src = hg + (size_t)(w * 32 + mt * 16 + l15) * FD
                             + kk * 32 + q8;
            hv[2 * mt]     = *(const float4*)src;
            hv[2 * mt + 1] = *(const float4*)(src + 4);
        }
        bf16x8 ah[2], al[2];
        #pragma unroll
        for (int mt = 0; mt < 2; ++mt) {
            const float4 f0 = hv[2 * mt], f1 = hv[2 * mt + 1];
            const float xs[8] = {f0.x, f0.y, f0.z, f0.w, f1.x, f1.y, f1.z, f1.w};
            union { bf16x8 v; unsigned u[4]; } H, L;
            #pragma unroll
            for (int j = 0; j < 4; ++j) {
                const unsigned e0 = __float_as_uint(xs[2 * j]);
                const unsigned e1 = __float_as_uint(xs[2 * j + 1]);
                H.u[j] = pack_top16(e1, e0);
                const unsigned l0 = rne_top16(xs[2*j]   - __uint_as_float(e0 & 0xffff0000u));
                const unsigned l1 = rne_top16(xs[2*j+1] - __uint_as_float(e1 & 0xffff0000u));
                L.u[j] = pack_top16(l1, l0);
            }
            ah[mt] = H.v; al[mt] = L.v;
        }
        #pragma unroll
        for (int nb = 0; nb < 8; ++nb) {
            const bf16x8 bh = *(const bf16x8*)&sWh[32768 + ((kk * 8 + nb) * 64 + lane) * 8];
            const bf16x8 bl = *(const bf16x8*)&sWh[49152 + ((kk * 8 + nb) * 64 + lane) * 8];
            #pragma unroll
            for (int mt = 0; mt < 2; ++mt) {
                acc1[mt][nb] = MFMA(al[mt], bh, acc1[mt][nb]);
                acc1[mt][nb] = MFMA(ah[mt], bl, acc1[mt][nb]);
                acc1[mt][nb] = MFMA(ah[mt], bh, acc1[mt][nb]);
            }
        }
    }

    // ---- esrc / edst for this wave's 32 rows -> LDS (pre-scaled LOG2E) ----
    {
        float av[8], bv[8];
        #pragma unroll
        for (int nb = 0; nb < 8; ++nb) {
            av[nb] = a[nb * 16 + l15];
            bv[nb] = a[FD + nb * 16 + l15];
        }
        #pragma unroll
        for (int mt = 0; mt < 2; ++mt)
            #pragma unroll
            for (int r = 0; r < 4; ++r) {
                float ps = 0.f, pd = 0.f;
                #pragma unroll
                for (int nb = 0; nb < 8; ++nb) {
                    ps += acc1[mt][nb][r] * av[nb];
                    pd += acc1[mt][nb][r] * bv[nb];
                }
                #pragma unroll
                for (int off = 1; off <= 8; off <<= 1) {
                    ps += __shfl_xor(ps, off);
                    pd += __shfl_xor(pd, off);
                }
                if (l15 == 0) {
                    const int row = w * 32 + mt * 16 + (lane >> 4) * 4 + r;
                    sEsrc[row] = ps * LOG2E;
                    sEdst[row] = pd * LOG2E;
                }
            }
    }
    __syncthreads();   // all waves done reading W region of sWh

    // ---- transpose this wave's 32 Wh rows into swizzled sWh (RNE bf16) ----
    {
        const int ib = 4 * ((lane >> 4) & 1);
        #pragma unroll
        for (int mt = 0; mt < 2; ++mt) {
            const int lp2 = l15 + 16 * (mt * 2 + (lane >> 5));
            #pragma unroll
            for (int nb = 0; nb < 8; ++nb) {
                const int off = ((w * 8 + nb) * 64 + lp2) * 8 + ib;
                const unsigned r0 = rne_top16(acc1[mt][nb][0]);
                const unsigned r1 = rne_top16(acc1[mt][nb][1]);
                const unsigned r2 = rne_top16(acc1[mt][nb][2]);
                const unsigned r3 = rne_top16(acc1[mt][nb][3]);
                *(uint2*)&sWh[off] = make_uint2(pack_top16(r1, r0), pack_top16(r3, r2));
            }
        }
    }
    __syncthreads();   // sWh / sEsrc / sEdst complete

    // ================= phase 2: attention, j-split wave pairs =================
    const int rg = w >> 1, jh = w & 1;
    const int rloc0 = rg * 32 + l15;                 // within the 256-half
    const int irow0 = hf * 256 + rloc0;              // node index
    const int irow1 = irow0 + 16;
    const float s0 = sEsrc[irow0];
    const float s1 = sEsrc[irow1];
    const int* adjr0 = adj + (size_t)irow0 * NN;
    const int* adjr1 = adj + (size_t)irow1 * NN;

    // register-constant B fragment: ones in column 0 (lane&15==0), else 0
    union { bf16x8 v; unsigned short s[8]; } bo;
    {
        const unsigned short oneb = (l15 == 0) ? (unsigned short)0x3f80 : (unsigned short)0;
        #pragma unroll
        for (int j = 0; j < 8; ++j) bo.s[j] = oneb;
    }

    f32x4 acc[2][8];
    #pragma unroll
    for (int mt = 0; mt < 2; ++mt)
        #pragma unroll
        for (int nb = 0; nb < 8; ++nb) acc[mt][nb] = (f32x4){0.f, 0.f, 0.f, 0.f};
    f32x4 accS0 = (f32x4){0.f, 0.f, 0.f, 0.f};
    f32x4 accS1 = (f32x4){0.f, 0.f, 0.f, 0.f};

    const int k0 = jh * 8;                           // this wave's KK range
    // adj pipelined one KK ahead (L2-resident, shared by all blocks)
    int4 n00 = *(const int4*)&adjr0[k0 * 32 + q8];
    int4 n01 = *(const int4*)&adjr0[k0 * 32 + q8 + 4];
    int4 n10 = *(const int4*)&adjr1[k0 * 32 + q8];
    int4 n11 = *(const int4*)&adjr1[k0 * 32 + q8 + 4];

    for (int kl = 0; kl < 8; ++kl) {
        const int KK = k0 + kl;
        const int4 m00 = n00, m01 = n01, m10 = n10, m11 = n11;
        if (kl < 7) {
            const int jb = (KK + 1) * 32 + q8;
            n00 = *(const int4*)&adjr0[jb];
            n01 = *(const int4*)&adjr0[jb + 4];
            n10 = *(const int4*)&adjr1[jb];
            n11 = *(const int4*)&adjr1[jb + 4];
        }
        const float* ep = &sEdst[KK * 32 + q8];
        const float4 ed0 = *(const float4*)ep;
        const float4 ed1 = *(const float4*)(ep + 4);
        const float ev[8] = {ed0.x, ed0.y, ed0.z, ed0.w, ed1.x, ed1.y, ed1.z, ed1.w};
        int ma0[8], ma1[8];
        *(int4*)&ma0[0] = m00; *(int4*)&ma0[4] = m01;
        *(int4*)&ma1[0] = m10; *(int4*)&ma1[4] = m11;

        union { bf16x8 v; unsigned u[4]; } H0, H1;
        unsigned uh0[8], uh1[8];
        #pragma unroll
        for (int i = 0; i < 8; ++i) {
            const float z0 = s0 + ev[i];
            float p0 = __builtin_amdgcn_exp2f(fmaxf(z0, 0.2f * z0));
            p0 = (ma0[i] > 0) ? p0 : 0.f;
            uh0[i] = __float_as_uint(p0);
            const float z1 = s1 + ev[i];
            float p1 = __builtin_amdgcn_exp2f(fmaxf(z1, 0.2f * z1));
            p1 = (ma1[i] > 0) ? p1 : 0.f;
            uh1[i] = __float_as_uint(p1);
        }
        #pragma unroll
        for (int j = 0; j < 4; ++j) {
            H0.u[j] = pack_top16(uh0[2*j+1], uh0[2*j]);   // perm keeps top16 = trunc
            H1.u[j] = pack_top16(uh1[2*j+1], uh1[2*j]);
        }
        #pragma unroll
        for (int nb = 0; nb < 8; ++nb) {
            const bf16x8 bh = *(const bf16x8*)&sWh[((KK * 8 + nb) * 64 + lane) * 8];
            acc[0][nb] = MFMA(H0.v, bh, acc[0][nb]);
            acc[1][nb] = MFMA(H1.v, bh, acc[1][nb]);
        }
        accS0 = MFMA(H0.v, bo.v, accS0);       // row-sums (lsum) in column 0
        accS1 = MFMA(H1.v, bo.v, accS1);
    }

    __syncthreads();   // ALL waves done reading sWh (jh=1 will overwrite it)

    float* sPartF = (float*)sWh;               // 32768 floats = 128 KB
    if (jh == 1) {
        #pragma unroll
        for (int mt = 0; mt < 2; ++mt)
            #pragma unroll
            for (int nb = 0; nb < 8; ++nb)
                *(f32x4*)&sPartF[(((rg * 2 + mt) * 8 + nb) * 64 + lane) * 4] = acc[mt][nb];
        if (l15 == 0) {
            #pragma unroll
            for (int r = 0; r < 4; ++r) {
                sEsrc[rg * 32 + (lane >> 4) * 4 + r]      = accS0[r];
                sEsrc[rg * 32 + 16 + (lane >> 4) * 4 + r] = accS1[r];
            }
        }
    }
    __syncthreads();

    if (jh == 0) {
        #pragma unroll
        for (int mt = 0; mt < 2; ++mt)
            #pragma unroll
            for (int nb = 0; nb < 8; ++nb) {
                const f32x4 p = *(const f32x4*)&sPartF[(((rg * 2 + mt) * 8 + nb) * 64 + lane) * 4];
                acc[mt][nb][0] += p[0]; acc[mt][nb][1] += p[1];
                acc[mt][nb][2] += p[2]; acc[mt][nb][3] += p[3];
            }
        #pragma unroll
        for (int r = 0; r < 4; ++r) {
            // own partial lsum at lane (lane&48), reg r, col 0; other half in sEsrc
            const float rl0 = 1.0f / (__shfl(accS0[r], lane & 48)
                                      + sEsrc[rg * 32 + (lane >> 4) * 4 + r]);
            const float rl1 = 1.0f / (__shfl(accS1[r], lane & 48)
                                      + sEsrc[rg * 32 + 16 + (lane >> 4) * 4 + r]);
            const int row0 = g * NN + hf * 256 + rg * 32 + (lane >> 4) * 4 + r;
            const int row1 = row0 + 16;
            #pragma unroll
            for (int nb = 0; nb < 8; ++nb) {
                out[row0 * FD + nb * 16 + l15] = acc[0][nb][r] * rl0;
                out[row1 * FD + nb * 16 + l15] = acc[1][nb][r] * rl1;
            }
        }
    }
}

// ---------------------------------------------------------------------------
extern "C" void kernel_launch(void* const* d_in, const int* in_sizes, int n_in,
                              void* d_out, int out_size, void* d_ws, size_t ws_size,
                              hipStream_t stream) {
    const float* h   = (const float*)d_in[0];
    const int*   adj = (const int*)d_in[1];
    const float* W   = (const float*)d_in[2];
    const float* a   = (const float*)d_in[3];
    float* out = (float*)d_out;
    (void)d_ws; (void)ws_size;   // workspace unused — all fused in LDS

    gat_fused_kernel<<<256, 1024, 0, stream>>>(h, a, adj, W, out);
}